// Round 4
// baseline (420.141 us; speedup 1.0000x reference)
//
#include <hip/hip_runtime.h>
#include <cstdint>
#include <cstddef>

#define I_DIM 1024
#define O_DIM 1024
#define B_DIM 128
#define T_DIM 100
#define ROWP 40  // LDS row pitch in ushorts (80 B): conflict-padded, 16B-aligned

typedef __attribute__((ext_vector_type(8))) __bf16 bf16x8;
typedef __attribute__((ext_vector_type(16))) float f32x16;

// round-to-nearest-even f32 -> bf16 bits
__device__ __forceinline__ unsigned short bf16rn(float x) {
  unsigned u = __float_as_uint(x);
  unsigned r = u + 0x7FFFu + ((u >> 16) & 1u);
  return (unsigned short)(r >> 16);
}
// two-term split: x ~= hi + lo, |x - hi - lo| <= 2^-16 |x|
__device__ __forceinline__ void split2(float x, unsigned short& h,
                                       unsigned short& l) {
  h = bf16rn(x);
  float hf = __uint_as_float(((unsigned)h) << 16);
  l = bf16rn(x - hf);
}

// ---------------------------------------------------------------------------
// wTt_hi/lo: w transposed, split, stored in MFMA-FRAGMENT-TILED layout:
// fragment (o-panel p of 32, k-chunk q of 16) holds 64 lanes x 16 B where
// lane l = (o&31) + 32*((a>>3)&1), inner = a&7. A wave's B-operand load is
// then ONE lane-contiguous global_load_dwordx4 (1 KB coalesced) -> no LDS.
// ---------------------------------------------------------------------------
__global__ __launch_bounds__(256) void split_wT_kernel(
    const float* __restrict__ w, unsigned short* __restrict__ wTth,
    unsigned short* __restrict__ wTtl) {
  __shared__ float tile[64][65];
  const int a0 = blockIdx.y * 64, o0 = blockIdx.x * 64;
  const int tid = threadIdx.x;
  const int tr = tid >> 4, tc4 = (tid & 15) * 4;
#pragma unroll
  for (int rr = 0; rr < 64; rr += 16) {
    float4 v = *(const float4*)&w[(size_t)(a0 + tr + rr) * O_DIM + o0 + tc4];
    tile[tr + rr][tc4 + 0] = v.x;
    tile[tr + rr][tc4 + 1] = v.y;
    tile[tr + rr][tc4 + 2] = v.z;
    tile[tr + rr][tc4 + 3] = v.w;
  }
  __syncthreads();
  const int q = (a0 >> 4) + (tc4 >> 4);
  const int kh = (tc4 >> 3) & 1;
  const int inner = tc4 & 7;  // 4-aligned within the 8-ushort fragment row
#pragma unroll
  for (int rr = 0; rr < 64; rr += 16) {
    int o = o0 + tr + rr;
    unsigned short hh[4], ll[4];
#pragma unroll
    for (int j = 0; j < 4; ++j) split2(tile[tc4 + j][tr + rr], hh[j], ll[j]);
    int l = (o & 31) + 32 * kh;
    size_t base = (((size_t)(o >> 5) * 64 + q) * 64 + l) * 8 + inner;
    *(ushort4*)&wTth[base] = make_ushort4(hh[0], hh[1], hh[2], hh[3]);
    *(ushort4*)&wTtl[base] = make_ushort4(ll[0], ll[1], ll[2], ll[3]);
  }
}

// ---------------------------------------------------------------------------
// norm[o] = sum_a w[a][o]^2 (f64). 16 WGs x 256 thr: 4 row-strided partials
// per column, LDS-reduced. 4x the waves of R3's version.
// ---------------------------------------------------------------------------
__global__ __launch_bounds__(256) void norm_kernel(
    const float* __restrict__ w, double* __restrict__ inv_norm) {
  __shared__ double red[4][64];
  const int tid = threadIdx.x;
  const int c = tid & 63, r = tid >> 6;
  const int o = blockIdx.x * 64 + c;
  double s = 0.0;
  for (int a = r; a < I_DIM; a += 4) {
    double t = (double)w[(size_t)a * O_DIM + o];
    s += t * t;
  }
  red[r][c] = s;
  __syncthreads();
  if (r == 0)
    inv_norm[o] = 1.0 / (red[0][c] + red[1][c] + red[2][c] + red[3][c] + 1e-8);
}

// ---------------------------------------------------------------------------
// M[i][o] = (1-beta)*v[i][o] - beta * sum_a w[a][i]*w[a][o]
// Fully LDS-free: A and B fragments both load directly from tiled wT
// (A-operand lane mapping == B-operand mapping). No barriers in the K-loop.
// ---------------------------------------------------------------------------
__global__ __launch_bounds__(256) void mbuild_mfma(
    const unsigned short* __restrict__ wTth,
    const unsigned short* __restrict__ wTtl, const float* __restrict__ v,
    const float* __restrict__ beta_p, float* __restrict__ M) {
  const int tid = threadIdx.x;
  const int i0 = blockIdx.y * 128, o0 = blockIdx.x * 128;
  const int wv = tid >> 6, lane = tid & 63;
  const int wm = wv >> 1, wn = wv & 1;
  const int lm = lane & 31, lkh = lane >> 5;
  f32x16 acc[2][2];
#pragma unroll
  for (int a = 0; a < 2; ++a)
#pragma unroll
    for (int b = 0; b < 2; ++b)
#pragma unroll
      for (int e = 0; e < 16; ++e) acc[a][b][e] = 0.f;
  const size_t pA0 = (i0 >> 5) + wm * 2;
  const size_t pB0 = (o0 >> 5) + wn * 2;
  for (int q = 0; q < 64; ++q) {
    bf16x8 ah[2], al[2], bh[2], bl[2];
#pragma unroll
    for (int mt = 0; mt < 2; ++mt) {
      size_t off = (((pA0 + mt) * 64 + q) * 64 + lane) * 8;
      ah[mt] = *(const bf16x8*)&wTth[off];
      al[mt] = *(const bf16x8*)&wTtl[off];
    }
#pragma unroll
    for (int nt = 0; nt < 2; ++nt) {
      size_t off = (((pB0 + nt) * 64 + q) * 64 + lane) * 8;
      bh[nt] = *(const bf16x8*)&wTth[off];
      bl[nt] = *(const bf16x8*)&wTtl[off];
    }
#pragma unroll
    for (int mt = 0; mt < 2; ++mt)
#pragma unroll
      for (int nt = 0; nt < 2; ++nt) {
        acc[mt][nt] = __builtin_amdgcn_mfma_f32_32x32x16_bf16(
            ah[mt], bh[nt], acc[mt][nt], 0, 0, 0);
        acc[mt][nt] = __builtin_amdgcn_mfma_f32_32x32x16_bf16(
            ah[mt], bl[nt], acc[mt][nt], 0, 0, 0);
        acc[mt][nt] = __builtin_amdgcn_mfma_f32_32x32x16_bf16(
            al[mt], bh[nt], acc[mt][nt], 0, 0, 0);
      }
  }
  const float beta = beta_p[0];
  const float ombeta = 1.0f - beta;
#pragma unroll
  for (int mt = 0; mt < 2; ++mt)
#pragma unroll
    for (int nt = 0; nt < 2; ++nt) {
      int col = o0 + wn * 64 + nt * 32 + lm;
#pragma unroll
      for (int r = 0; r < 16; ++r) {
        int row = i0 + wm * 64 + mt * 32 + (r & 3) + 8 * (r >> 2) + 4 * lkh;
        M[(size_t)row * O_DIM + col] =
            ombeta * v[(size_t)row * O_DIM + col] - beta * acc[mt][nt][r];
      }
    }
}

// ---------------------------------------------------------------------------
// hgemm: A (x, split in-kernel) via DOUBLE-BUFFERED LDS (1 barrier/chunk);
// B fragments direct from L2-resident tiled wT (no LDS, no staging writes).
// LDS traffic per chunk halves vs R3; barrier drains halve.
// ---------------------------------------------------------------------------
__device__ __forceinline__ void store_split16(unsigned short* dh,
                                              unsigned short* dl, float4 v0,
                                              float4 v1, float4 v2, float4 v3) {
  float vals[16] = {v0.x, v0.y, v0.z, v0.w, v1.x, v1.y, v1.z, v1.w,
                    v2.x, v2.y, v2.z, v2.w, v3.x, v3.y, v3.z, v3.w};
  unsigned short hh[16], ll[16];
#pragma unroll
  for (int i = 0; i < 16; ++i) split2(vals[i], hh[i], ll[i]);
#pragma unroll
  for (int i = 0; i < 4; ++i) {
    *(ushort4*)&dh[4 * i] =
        make_ushort4(hh[4 * i], hh[4 * i + 1], hh[4 * i + 2], hh[4 * i + 3]);
    *(ushort4*)&dl[4 * i] =
        make_ushort4(ll[4 * i], ll[4 * i + 1], ll[4 * i + 2], ll[4 * i + 3]);
  }
}

__global__ __launch_bounds__(256) void hgemm_mfma(
    const float* __restrict__ x, const unsigned short* __restrict__ wTth,
    const unsigned short* __restrict__ wTtl, float* __restrict__ h) {
  __shared__ unsigned short Ah[2][128 * ROWP];
  __shared__ unsigned short Al[2][128 * ROWP];
  const int tid = threadIdx.x;
  const int row0 = blockIdx.y * 128, col0 = blockIdx.x * 128;
  const int wv = tid >> 6, lane = tid & 63;
  const int wm = wv >> 1, wn = wv & 1;
  const int lm = lane & 31, lkh = lane >> 5;
  const int sm = tid >> 1, sko = (tid & 1) * 16;
  f32x16 acc[2][2];
#pragma unroll
  for (int a = 0; a < 2; ++a)
#pragma unroll
    for (int b = 0; b < 2; ++b)
#pragma unroll
      for (int e = 0; e < 16; ++e) acc[a][b][e] = 0.f;
  const size_t pB0 = (col0 >> 5) + wn * 2;
  const float* xp = x + (size_t)(row0 + sm) * I_DIM + sko;

  {  // prologue: stage chunk 0 into buf 0
    float4 v0 = *(const float4*)(xp + 0);
    float4 v1 = *(const float4*)(xp + 4);
    float4 v2 = *(const float4*)(xp + 8);
    float4 v3 = *(const float4*)(xp + 12);
    store_split16(&Ah[0][sm * ROWP + sko], &Al[0][sm * ROWP + sko], v0, v1, v2,
                  v3);
  }
  bf16x8 bh[2][2], bl[2][2];  // [nt][kq]
#pragma unroll
  for (int nt = 0; nt < 2; ++nt)
#pragma unroll
    for (int kq = 0; kq < 2; ++kq) {
      size_t off = (((pB0 + nt) * 64 + kq) * 64 + lane) * 8;
      bh[nt][kq] = *(const bf16x8*)&wTth[off];
      bl[nt][kq] = *(const bf16x8*)&wTtl[off];
    }
  __syncthreads();

  for (int c = 0; c < 32; ++c) {
    const int cb = c & 1;
    float4 n0, n1, n2, n3;
    bf16x8 nbh[2][2], nbl[2][2];
    if (c < 31) {  // prefetch next chunk: x (for LDS) + B frags (regs)
      const float* xn = xp + (c + 1) * 32;
      n0 = *(const float4*)(xn + 0);
      n1 = *(const float4*)(xn + 4);
      n2 = *(const float4*)(xn + 8);
      n3 = *(const float4*)(xn + 12);
#pragma unroll
      for (int nt = 0; nt < 2; ++nt)
#pragma unroll
        for (int kq = 0; kq < 2; ++kq) {
          size_t off =
              (((pB0 + nt) * 64 + (2 * (c + 1) + kq)) * 64 + lane) * 8;
          nbh[nt][kq] = *(const bf16x8*)&wTth[off];
          nbl[nt][kq] = *(const bf16x8*)&wTtl[off];
        }
    }
    bf16x8 fah[2][2], fal[2][2];  // [mt][kq]
#pragma unroll
    for (int mt = 0; mt < 2; ++mt)
#pragma unroll
      for (int kq = 0; kq < 2; ++kq) {
        int off = (wm * 64 + mt * 32 + lm) * ROWP + kq * 16 + lkh * 8;
        fah[mt][kq] = *(const bf16x8*)&Ah[cb][off];
        fal[mt][kq] = *(const bf16x8*)&Al[cb][off];
      }
    // same accumulation order as R3 (validated): kq outer, mt, nt, hh/hl/lh
#pragma unroll
    for (int kq = 0; kq < 2; ++kq)
#pragma unroll
      for (int mt = 0; mt < 2; ++mt)
#pragma unroll
        for (int nt = 0; nt < 2; ++nt) {
          acc[mt][nt] = __builtin_amdgcn_mfma_f32_32x32x16_bf16(
              fah[mt][kq], bh[nt][kq], acc[mt][nt], 0, 0, 0);
          acc[mt][nt] = __builtin_amdgcn_mfma_f32_32x32x16_bf16(
              fah[mt][kq], bl[nt][kq], acc[mt][nt], 0, 0, 0);
          acc[mt][nt] = __builtin_amdgcn_mfma_f32_32x32x16_bf16(
              fal[mt][kq], bh[nt][kq], acc[mt][nt], 0, 0, 0);
        }
    if (c < 31) {
      store_split16(&Ah[cb ^ 1][sm * ROWP + sko], &Al[cb ^ 1][sm * ROWP + sko],
                    n0, n1, n2, n3);
      __syncthreads();  // the ONLY barrier per chunk
#pragma unroll
      for (int nt = 0; nt < 2; ++nt)
#pragma unroll
        for (int kq = 0; kq < 2; ++kq) {
          bh[nt][kq] = nbh[nt][kq];
          bl[nt][kq] = nbl[nt][kq];
        }
    }
  }
#pragma unroll
  for (int mt = 0; mt < 2; ++mt)
#pragma unroll
    for (int nt = 0; nt < 2; ++nt) {
      int col = col0 + wn * 64 + nt * 32 + lm;
#pragma unroll
      for (int r = 0; r < 16; ++r) {
        int row = row0 + wm * 64 + mt * 32 + (r & 3) + 8 * (r >> 2) + 4 * lkh;
        h[(size_t)row * O_DIM + col] = acc[mt][nt][r];
      }
    }
}

// ---------------------------------------------------------------------------
// Scan: ONE barrier per step. Per-wave spike lists (parity double-buffered)
// appended with ballot+mbcnt — no LDS atomics, no reset (unconditional
// overwrite of the opposite parity). No-spike fast path skips the gather.
// ---------------------------------------------------------------------------
__global__ __launch_bounds__(256) void scan_kernel(
    const float* __restrict__ h, const float* __restrict__ M,
    const double* __restrict__ inv_norm, const float* __restrict__ bvec,
    const float* __restrict__ beta_p, float* __restrict__ out,
    int* __restrict__ counts) {
  __shared__ unsigned short wlist[2][4][256];
  __shared__ int wcnt[2][4];
  const int b = blockIdx.x, tid = threadIdx.x;
  const int wv = tid >> 6;
  const double beta = (double)beta_p[0];
  const double ombeta = 1.0 - beta;
  double mem[4] = {0.0, 0.0, 0.0, 0.0};
  double inv[4], bth[4];
  int o[4];
#pragma unroll
  for (int j = 0; j < 4; ++j) {
    o[j] = tid + j * 256;
    inv[j] = inv_norm[o[j]];
    bth[j] = (double)bvec[o[j]];
  }
  if (tid < 8) wcnt[tid >> 2][tid & 3] = 0;
  __syncthreads();
  const float* hb = h + (size_t)b * T_DIM * O_DIM;
  float* ob = out + (size_t)b * T_DIM * O_DIM;
  float hv[4];
#pragma unroll
  for (int j = 0; j < 4; ++j) hv[j] = hb[o[j]];
  for (int t = 0; t < T_DIM; ++t) {
    const int p = t & 1, np = p ^ 1;
    float hvn[4] = {0.f, 0.f, 0.f, 0.f};
    if (t + 1 < T_DIM) {
#pragma unroll
      for (int j = 0; j < 4; ++j) hvn[j] = hb[(size_t)(t + 1) * O_DIM + o[j]];
    }
    double lat[4] = {0.0, 0.0, 0.0, 0.0};
    const int ks = wcnt[p][0] + wcnt[p][1] + wcnt[p][2] + wcnt[p][3];
    if (ks) {
#pragma unroll
      for (int w = 0; w < 4; ++w) {
        const int kw = wcnt[p][w];
        for (int n = 0; n < kw; ++n) {
          const int i = wlist[p][w][n];
          const float* Mrow = M + (size_t)i * O_DIM;
#pragma unroll
          for (int j = 0; j < 4; ++j) lat[j] += (double)Mrow[o[j]];
        }
      }
    }
    unsigned cur = 0;
#pragma unroll
    for (int j = 0; j < 4; ++j) {
      mem[j] = mem[j] * beta + (double)hv[j] * ombeta + lat[j];
      double mthr = mem[j] * inv[j] - bth[j];
      bool s = mthr > 0.0;
      ob[(size_t)t * O_DIM + o[j]] = s ? 1.0f : 0.0f;
      unsigned long long mask = __ballot(s);
      if (s) {
        unsigned below = __builtin_amdgcn_mbcnt_lo((unsigned)mask, 0);
        below = __builtin_amdgcn_mbcnt_hi((unsigned)(mask >> 32), below);
        wlist[np][wv][cur + below] = (unsigned short)o[j];
      }
      cur += (unsigned)__popcll(mask);
      hv[j] = hvn[j];
    }
    if ((tid & 63) == 0) wcnt[np][wv] = (int)cur;
    __syncthreads();
    if (tid == 0)
      atomicAdd(&counts[t],
                wcnt[np][0] + wcnt[np][1] + wcnt[np][2] + wcnt[np][3]);
  }
}

__global__ void finalize_kernel(const int* __restrict__ counts,
                                float* __restrict__ out) {
  if (threadIdx.x == 0) {
    long long total = 0;
    int mx = 0;
    for (int t = 0; t < T_DIM; ++t) {
      total += counts[t];
      if (counts[t] > mx) mx = counts[t];
    }
    const double N = (double)B_DIM * T_DIM * O_DIM;
    out[(size_t)B_DIM * T_DIM * O_DIM] = (float)(0.5 * (double)total / N);
    out[(size_t)B_DIM * T_DIM * O_DIM + 1] =
        (float)((double)mx / (double)(B_DIM * O_DIM));
  }
}

extern "C" void kernel_launch(void* const* d_in, const int* in_sizes, int n_in,
                              void* d_out, int out_size, void* d_ws,
                              size_t ws_size, hipStream_t stream) {
  const float* x = (const float*)d_in[0];
  const float* w = (const float*)d_in[1];
  const float* v = (const float*)d_in[2];
  const float* beta = (const float*)d_in[3];
  const float* b = (const float*)d_in[4];
  float* out = (float*)d_out;

  char* ws = (char*)d_ws;
  // M f32 4MB | h f32 50MB | wTt_hi 2MB | wTt_lo 2MB | inv_norm 8KB | counts
  float* M = (float*)ws;
  float* h = (float*)(ws + 4194304);
  unsigned short* wTth = (unsigned short*)(ws + 4194304 + 52428800);
  unsigned short* wTtl = (unsigned short*)(ws + 4194304 + 52428800 + 2097152);
  double* invn = (double*)(ws + 4194304 + 52428800 + 4194304);
  int* counts = (int*)(ws + 4194304 + 52428800 + 4194304 + 8192);

  hipLaunchKernelGGL(split_wT_kernel, dim3(16, 16), dim3(256), 0, stream, w,
                     wTth, wTtl);
  hipLaunchKernelGGL(norm_kernel, dim3(16), dim3(256), 0, stream, w, invn);
  hipLaunchKernelGGL(mbuild_mfma, dim3(8, 8), dim3(256), 0, stream, wTth, wTtl,
                     v, beta, M);
  hipLaunchKernelGGL(hgemm_mfma, dim3(8, 100), dim3(256), 0, stream, x, wTth,
                     wTtl, h);
  hipMemsetAsync(counts, 0, T_DIM * sizeof(int), stream);
  hipLaunchKernelGGL(scan_kernel, dim3(128), dim3(256), 0, stream, h, M, invn,
                     b, beta, out, counts);
  hipLaunchKernelGGL(finalize_kernel, dim3(1), dim3(64), 0, stream, counts,
                     out);
}

// Round 6
// 403.231 us; speedup vs baseline: 1.0419x; 1.0419x over previous
//
#include <hip/hip_runtime.h>
#include <cstdint>
#include <cstddef>

#define I_DIM 1024
#define O_DIM 1024
#define B_DIM 128
#define T_DIM 100
#define ROWP 40     // LDS row pitch (ushorts) for fallback hgemm
#define PANEL 32768 // fragment-tiled panel stride in ushorts = 64q * 64lane * 8
#define QSTep 512   // per-q stride in ushorts = 64 lanes * 8

typedef __attribute__((ext_vector_type(8))) __bf16 bf16x8;
typedef __attribute__((ext_vector_type(16))) float f32x16;

__device__ __forceinline__ unsigned short bf16rn(float x) {
  unsigned u = __float_as_uint(x);
  unsigned r = u + 0x7FFFu + ((u >> 16) & 1u);
  return (unsigned short)(r >> 16);
}
__device__ __forceinline__ void split2(float x, unsigned short& h,
                                       unsigned short& l) {
  h = bf16rn(x);
  float hf = __uint_as_float(((unsigned)h) << 16);
  l = bf16rn(x - hf);
}

// ---------------------------------------------------------------------------
// split_wT: w -> transposed, split, MFMA-fragment-tiled wTt_hi/lo.
// Fragment (panel p=o>>5, q=a>>4): lane=(o&31)+32*((a>>3)&1), inner=a&7.
// Also emits norm partials normpart[a0>>6][o] (f64, deterministic).
// ---------------------------------------------------------------------------
__global__ __launch_bounds__(256) void split_wT_kernel(
    const float* __restrict__ w, unsigned short* __restrict__ wTth,
    unsigned short* __restrict__ wTtl, double* __restrict__ normpart) {
  __shared__ float tile[64][65];
  __shared__ double red[4][64];
  const int a0 = blockIdx.y * 64, o0 = blockIdx.x * 64;
  const int tid = threadIdx.x;
  const int tr = tid >> 4, tc4 = (tid & 15) * 4;
#pragma unroll
  for (int rr = 0; rr < 64; rr += 16) {
    float4 v = *(const float4*)&w[(size_t)(a0 + tr + rr) * O_DIM + o0 + tc4];
    tile[tr + rr][tc4 + 0] = v.x;
    tile[tr + rr][tc4 + 1] = v.y;
    tile[tr + rr][tc4 + 2] = v.z;
    tile[tr + rr][tc4 + 3] = v.w;
  }
  __syncthreads();
  {
    const int ol = tid & 63, seg = tid >> 6;
    double s = 0.0;
#pragma unroll
    for (int i = 0; i < 16; ++i) {
      double v = (double)tile[seg * 16 + i][ol];
      s += v * v;
    }
    red[seg][ol] = s;
  }
  const int q = (a0 >> 4) + (tc4 >> 4);
  const int kh = (tc4 >> 3) & 1;
  const int inner = tc4 & 7;
#pragma unroll
  for (int rr = 0; rr < 64; rr += 16) {
    int o = o0 + tr + rr;
    unsigned short hh[4], ll[4];
#pragma unroll
    for (int j = 0; j < 4; ++j) split2(tile[tc4 + j][tr + rr], hh[j], ll[j]);
    int l = (o & 31) + 32 * kh;
    size_t base = ((size_t)(o >> 5) * PANEL) + (size_t)q * QSTep +
                  (size_t)l * 8 + inner;
    *(ushort4*)&wTth[base] = make_ushort4(hh[0], hh[1], hh[2], hh[3]);
    *(ushort4*)&wTtl[base] = make_ushort4(ll[0], ll[1], ll[2], ll[3]);
  }
  __syncthreads();
  if (tid < 64)
    normpart[(size_t)(a0 >> 6) * O_DIM + o0 + tid] =
        red[0][tid] + red[1][tid] + red[2][tid] + red[3][tid];
}

// ---------------------------------------------------------------------------
// xsplit: x -> split + fragment-tiled xt_hi/lo (A-operand layout == the
// R4-HW-validated B layout). 400 row-panels; same split2 values as R4's
// in-kernel split -> h stays bit-identical.
// ---------------------------------------------------------------------------
__global__ __launch_bounds__(256) void xsplit_kernel(
    const float* __restrict__ x, unsigned short* __restrict__ xth,
    unsigned short* __restrict__ xtl) {
  const int p = blockIdx.x;
  const int tid = threadIdx.x;
  const int wq = tid >> 6, lane = tid & 63;
  const int row = lane & 31, kh = lane >> 5;
  const float* src = x + (size_t)(p * 32 + row) * I_DIM + kh * 8;
#pragma unroll 4
  for (int i = 0; i < 16; ++i) {
    const int q = i * 4 + wq;
    const float* s = src + q * 16;
    float4 v0 = *(const float4*)(s);
    float4 v1 = *(const float4*)(s + 4);
    unsigned short h[8], l[8];
    split2(v0.x, h[0], l[0]);
    split2(v0.y, h[1], l[1]);
    split2(v0.z, h[2], l[2]);
    split2(v0.w, h[3], l[3]);
    split2(v1.x, h[4], l[4]);
    split2(v1.y, h[5], l[5]);
    split2(v1.z, h[6], l[6]);
    split2(v1.w, h[7], l[7]);
    size_t base = ((size_t)p * PANEL) + (size_t)q * QSTep + (size_t)lane * 8;
    *(ushort4*)&xth[base] = make_ushort4(h[0], h[1], h[2], h[3]);
    *(ushort4*)&xth[base + 4] = make_ushort4(h[4], h[5], h[6], h[7]);
    *(ushort4*)&xtl[base] = make_ushort4(l[0], l[1], l[2], l[3]);
    *(ushort4*)&xtl[base + 4] = make_ushort4(l[4], l[5], l[6], l[7]);
  }
}

// ---------------------------------------------------------------------------
// mbuild: M[i][o] = (1-beta)*v[i][o] - beta*(w^T w)[i][o]. LDS-free,
// barrier-free, 64x64 tile (grid 16x16 = 256 WGs), 1-q-deep prefetch.
// ---------------------------------------------------------------------------
__global__ __launch_bounds__(256) void mbuild_mfma(
    const unsigned short* __restrict__ wTth,
    const unsigned short* __restrict__ wTtl, const float* __restrict__ v,
    const float* __restrict__ beta_p, float* __restrict__ M) {
  const int tid = threadIdx.x;
  const int i0 = blockIdx.y * 64, o0 = blockIdx.x * 64;
  const int wv = tid >> 6, lane = tid & 63;
  const int wm = wv >> 1, wn = wv & 1;
  const int lm = lane & 31, lkh = lane >> 5;
  f32x16 acc;
#pragma unroll
  for (int e = 0; e < 16; ++e) acc[e] = 0.f;
  const size_t offA =
      ((size_t)((i0 >> 5) + wm) * PANEL) + (size_t)lane * 8;  // panel stride!
  const size_t offB = ((size_t)((o0 >> 5) + wn) * PANEL) + (size_t)lane * 8;
  bf16x8 ah[2], al[2], bh[2], bl[2];
  ah[0] = *(const bf16x8*)(wTth + offA);
  al[0] = *(const bf16x8*)(wTtl + offA);
  bh[0] = *(const bf16x8*)(wTth + offB);
  bl[0] = *(const bf16x8*)(wTtl + offB);
#pragma unroll 2
  for (int q = 0; q < 64; ++q) {
    const int cb = q & 1;
    if (q < 63) {
      size_t d = (size_t)(q + 1) * QSTep;
      ah[cb ^ 1] = *(const bf16x8*)(wTth + offA + d);
      al[cb ^ 1] = *(const bf16x8*)(wTtl + offA + d);
      bh[cb ^ 1] = *(const bf16x8*)(wTth + offB + d);
      bl[cb ^ 1] = *(const bf16x8*)(wTtl + offB + d);
    }
    acc = __builtin_amdgcn_mfma_f32_32x32x16_bf16(ah[cb], bh[cb], acc, 0, 0, 0);
    acc = __builtin_amdgcn_mfma_f32_32x32x16_bf16(ah[cb], bl[cb], acc, 0, 0, 0);
    acc = __builtin_amdgcn_mfma_f32_32x32x16_bf16(al[cb], bh[cb], acc, 0, 0, 0);
  }
  const float beta = beta_p[0];
  const float ombeta = 1.0f - beta;
  const int col = o0 + wn * 32 + lm;
#pragma unroll
  for (int r = 0; r < 16; ++r) {
    int row = i0 + wm * 32 + (r & 3) + 8 * (r >> 2) + 4 * lkh;
    M[(size_t)row * O_DIM + col] =
        ombeta * v[(size_t)row * O_DIM + col] - beta * acc[r];
  }
}

// ---------------------------------------------------------------------------
// hgemm_direct (main path): ZERO LDS, ZERO barriers. Both operands stream
// from fragment-tiled global buffers with 1-q register double-buffer.
// Pass-outer MFMA order; per-accumulator summation order (q asc; hh,hl,lh)
// identical to R3/R4 -> bit-identical h.
// ---------------------------------------------------------------------------
__global__ __launch_bounds__(256) void hgemm_direct(
    const unsigned short* __restrict__ xth,
    const unsigned short* __restrict__ xtl,
    const unsigned short* __restrict__ wTth,
    const unsigned short* __restrict__ wTtl, float* __restrict__ h) {
  const int tid = threadIdx.x;
  const int row0 = blockIdx.y * 128, col0 = blockIdx.x * 128;
  const int wv = tid >> 6, lane = tid & 63;
  const int wm = wv >> 1, wn = wv & 1;
  const int lm = lane & 31, lkh = lane >> 5;
  f32x16 acc[2][2];
#pragma unroll
  for (int a = 0; a < 2; ++a)
#pragma unroll
    for (int b = 0; b < 2; ++b)
#pragma unroll
      for (int e = 0; e < 16; ++e) acc[a][b][e] = 0.f;
  const unsigned short *pah[2], *pal[2], *pbh[2], *pbl[2];
#pragma unroll
  for (int t = 0; t < 2; ++t) {
    size_t offA = ((size_t)((row0 >> 5) + wm * 2 + t) * PANEL) +
                  (size_t)lane * 8;  // panel stride fixed (R5 bug: was 4096)
    size_t offB = ((size_t)((col0 >> 5) + wn * 2 + t) * PANEL) +
                  (size_t)lane * 8;
    pah[t] = xth + offA;
    pal[t] = xtl + offA;
    pbh[t] = wTth + offB;
    pbl[t] = wTtl + offB;
  }
  bf16x8 fah[2][2], fal[2][2], fbh[2][2], fbl[2][2];  // [buf][tile]
#pragma unroll
  for (int t = 0; t < 2; ++t) {
    fah[0][t] = *(const bf16x8*)(pah[t]);
    fal[0][t] = *(const bf16x8*)(pal[t]);
    fbh[0][t] = *(const bf16x8*)(pbh[t]);
    fbl[0][t] = *(const bf16x8*)(pbl[t]);
  }
#pragma unroll 2
  for (int q = 0; q < 64; ++q) {
    const int cb = q & 1;
    if (q < 63) {
      size_t d = (size_t)(q + 1) * QSTep;
#pragma unroll
      for (int t = 0; t < 2; ++t) {
        fah[cb ^ 1][t] = *(const bf16x8*)(pah[t] + d);
        fal[cb ^ 1][t] = *(const bf16x8*)(pal[t] + d);
        fbh[cb ^ 1][t] = *(const bf16x8*)(pbh[t] + d);
        fbl[cb ^ 1][t] = *(const bf16x8*)(pbl[t] + d);
      }
    }
#pragma unroll
    for (int mt = 0; mt < 2; ++mt)
#pragma unroll
      for (int nt = 0; nt < 2; ++nt)
        acc[mt][nt] = __builtin_amdgcn_mfma_f32_32x32x16_bf16(
            fah[cb][mt], fbh[cb][nt], acc[mt][nt], 0, 0, 0);
#pragma unroll
    for (int mt = 0; mt < 2; ++mt)
#pragma unroll
      for (int nt = 0; nt < 2; ++nt)
        acc[mt][nt] = __builtin_amdgcn_mfma_f32_32x32x16_bf16(
            fah[cb][mt], fbl[cb][nt], acc[mt][nt], 0, 0, 0);
#pragma unroll
    for (int mt = 0; mt < 2; ++mt)
#pragma unroll
      for (int nt = 0; nt < 2; ++nt)
        acc[mt][nt] = __builtin_amdgcn_mfma_f32_32x32x16_bf16(
            fal[cb][mt], fbh[cb][nt], acc[mt][nt], 0, 0, 0);
  }
#pragma unroll
  for (int mt = 0; mt < 2; ++mt)
#pragma unroll
    for (int nt = 0; nt < 2; ++nt) {
      int col = col0 + wn * 64 + nt * 32 + lm;
#pragma unroll
      for (int r = 0; r < 16; ++r) {
        int row = row0 + wm * 64 + mt * 32 + (r & 3) + 8 * (r >> 2) + 4 * lkh;
        h[(size_t)row * O_DIM + col] = acc[mt][nt][r];
      }
    }
}

// ---------------------------------------------------------------------------
// hgemm_lds (fallback if ws too small for xt): exact R4-validated kernel.
// ---------------------------------------------------------------------------
__device__ __forceinline__ void store_split16(unsigned short* dh,
                                              unsigned short* dl, float4 v0,
                                              float4 v1, float4 v2, float4 v3) {
  float vals[16] = {v0.x, v0.y, v0.z, v0.w, v1.x, v1.y, v1.z, v1.w,
                    v2.x, v2.y, v2.z, v2.w, v3.x, v3.y, v3.z, v3.w};
  unsigned short hh[16], ll[16];
#pragma unroll
  for (int i = 0; i < 16; ++i) split2(vals[i], hh[i], ll[i]);
#pragma unroll
  for (int i = 0; i < 4; ++i) {
    *(ushort4*)&dh[4 * i] =
        make_ushort4(hh[4 * i], hh[4 * i + 1], hh[4 * i + 2], hh[4 * i + 3]);
    *(ushort4*)&dl[4 * i] =
        make_ushort4(ll[4 * i], ll[4 * i + 1], ll[4 * i + 2], ll[4 * i + 3]);
  }
}

__global__ __launch_bounds__(256) void hgemm_lds(
    const float* __restrict__ x, const unsigned short* __restrict__ wTth,
    const unsigned short* __restrict__ wTtl, float* __restrict__ h) {
  __shared__ unsigned short Ah[2][128 * ROWP];
  __shared__ unsigned short Al[2][128 * ROWP];
  const int tid = threadIdx.x;
  const int row0 = blockIdx.y * 128, col0 = blockIdx.x * 128;
  const int wv = tid >> 6, lane = tid & 63;
  const int wm = wv >> 1, wn = wv & 1;
  const int lm = lane & 31, lkh = lane >> 5;
  const int sm = tid >> 1, sko = (tid & 1) * 16;
  f32x16 acc[2][2];
#pragma unroll
  for (int a = 0; a < 2; ++a)
#pragma unroll
    for (int b = 0; b < 2; ++b)
#pragma unroll
      for (int e = 0; e < 16; ++e) acc[a][b][e] = 0.f;
  const size_t pB0 = (col0 >> 5) + wn * 2;
  const float* xp = x + (size_t)(row0 + sm) * I_DIM + sko;
  {
    float4 v0 = *(const float4*)(xp + 0);
    float4 v1 = *(const float4*)(xp + 4);
    float4 v2 = *(const float4*)(xp + 8);
    float4 v3 = *(const float4*)(xp + 12);
    store_split16(&Ah[0][sm * ROWP + sko], &Al[0][sm * ROWP + sko], v0, v1, v2,
                  v3);
  }
  bf16x8 bh[2][2], bl[2][2];
#pragma unroll
  for (int nt = 0; nt < 2; ++nt)
#pragma unroll
    for (int kq = 0; kq < 2; ++kq) {
      size_t off =
          ((pB0 + nt) * PANEL) + (size_t)kq * QSTep + (size_t)lane * 8;
      bh[nt][kq] = *(const bf16x8*)&wTth[off];
      bl[nt][kq] = *(const bf16x8*)&wTtl[off];
    }
  __syncthreads();
  for (int c = 0; c < 32; ++c) {
    const int cb = c & 1;
    float4 n0, n1, n2, n3;
    bf16x8 nbh[2][2], nbl[2][2];
    if (c < 31) {
      const float* xn = xp + (c + 1) * 32;
      n0 = *(const float4*)(xn + 0);
      n1 = *(const float4*)(xn + 4);
      n2 = *(const float4*)(xn + 8);
      n3 = *(const float4*)(xn + 12);
#pragma unroll
      for (int nt = 0; nt < 2; ++nt)
#pragma unroll
        for (int kq = 0; kq < 2; ++kq) {
          size_t off = ((pB0 + nt) * PANEL) +
                       (size_t)(2 * (c + 1) + kq) * QSTep + (size_t)lane * 8;
          nbh[nt][kq] = *(const bf16x8*)&wTth[off];
          nbl[nt][kq] = *(const bf16x8*)&wTtl[off];
        }
    }
    bf16x8 fah[2][2], fal[2][2];
#pragma unroll
    for (int mt = 0; mt < 2; ++mt)
#pragma unroll
      for (int kq = 0; kq < 2; ++kq) {
        int off = (wm * 64 + mt * 32 + lm) * ROWP + kq * 16 + lkh * 8;
        fah[mt][kq] = *(const bf16x8*)&Ah[cb][off];
        fal[mt][kq] = *(const bf16x8*)&Al[cb][off];
      }
#pragma unroll
    for (int kq = 0; kq < 2; ++kq) {
#pragma unroll
      for (int mt = 0; mt < 2; ++mt)
#pragma unroll
        for (int nt = 0; nt < 2; ++nt)
          acc[mt][nt] = __builtin_amdgcn_mfma_f32_32x32x16_bf16(
              fah[mt][kq], bh[nt][kq], acc[mt][nt], 0, 0, 0);
#pragma unroll
      for (int mt = 0; mt < 2; ++mt)
#pragma unroll
        for (int nt = 0; nt < 2; ++nt)
          acc[mt][nt] = __builtin_amdgcn_mfma_f32_32x32x16_bf16(
              fah[mt][kq], bl[nt][kq], acc[mt][nt], 0, 0, 0);
#pragma unroll
      for (int mt = 0; mt < 2; ++mt)
#pragma unroll
        for (int nt = 0; nt < 2; ++nt)
          acc[mt][nt] = __builtin_amdgcn_mfma_f32_32x32x16_bf16(
              fal[mt][kq], bh[nt][kq], acc[mt][nt], 0, 0, 0);
    }
    if (c < 31) {
      store_split16(&Ah[cb ^ 1][sm * ROWP + sko], &Al[cb ^ 1][sm * ROWP + sko],
                    n0, n1, n2, n3);
      __syncthreads();
#pragma unroll
      for (int nt = 0; nt < 2; ++nt)
#pragma unroll
        for (int kq = 0; kq < 2; ++kq) {
          bh[nt][kq] = nbh[nt][kq];
          bl[nt][kq] = nbl[nt][kq];
        }
    }
  }
#pragma unroll
  for (int mt = 0; mt < 2; ++mt)
#pragma unroll
    for (int nt = 0; nt < 2; ++nt) {
      int col = col0 + wn * 64 + nt * 32 + lm;
#pragma unroll
      for (int r = 0; r < 16; ++r) {
        int row = row0 + wm * 64 + mt * 32 + (r & 3) + 8 * (r >> 2) + 4 * lkh;
        h[(size_t)row * O_DIM + col] = acc[mt][nt][r];
      }
    }
}

// ---------------------------------------------------------------------------
// Scan: R4-validated structure (__syncthreads). inv from normpart; 2-step
// h prefetch; per-wave ballot spike lists.
// ---------------------------------------------------------------------------
__global__ __launch_bounds__(256) void scan_kernel(
    const float* __restrict__ h, const float* __restrict__ M,
    const double* __restrict__ normpart, const float* __restrict__ bvec,
    const float* __restrict__ beta_p, float* __restrict__ out,
    int* __restrict__ counts) {
  __shared__ unsigned short wlist[2][4][256];
  __shared__ int wcnt[2][4];
  const int b = blockIdx.x, tid = threadIdx.x;
  const int wv = tid >> 6;
  const double beta = (double)beta_p[0];
  const double ombeta = 1.0 - beta;
  double mem[4] = {0.0, 0.0, 0.0, 0.0};
  double inv[4], bth[4];
  int o[4];
#pragma unroll
  for (int j = 0; j < 4; ++j) {
    o[j] = tid + j * 256;
    double s = 0.0;
#pragma unroll
    for (int g = 0; g < 16; ++g) s += normpart[(size_t)g * O_DIM + o[j]];
    inv[j] = 1.0 / (s + 1e-8);
    bth[j] = (double)bvec[o[j]];
  }
  if (tid < 8) wcnt[tid >> 2][tid & 3] = 0;
  __syncthreads();
  const float* hb = h + (size_t)b * T_DIM * O_DIM;
  float* ob = out + (size_t)b * T_DIM * O_DIM;
  float hv0[4], hv1[4];
#pragma unroll
  for (int j = 0; j < 4; ++j) {
    hv0[j] = hb[o[j]];
    hv1[j] = hb[O_DIM + o[j]];
  }
  for (int t = 0; t < T_DIM; ++t) {
    const int p = t & 1, np = p ^ 1;
    float hv2[4] = {0.f, 0.f, 0.f, 0.f};
    if (t + 2 < T_DIM) {
#pragma unroll
      for (int j = 0; j < 4; ++j) hv2[j] = hb[(size_t)(t + 2) * O_DIM + o[j]];
    }
    double lat[4] = {0.0, 0.0, 0.0, 0.0};
    const int ks = wcnt[p][0] + wcnt[p][1] + wcnt[p][2] + wcnt[p][3];
    if (ks) {
#pragma unroll
      for (int w = 0; w < 4; ++w) {
        const int kw = wcnt[p][w];
        for (int n = 0; n < kw; ++n) {
          const int i = wlist[p][w][n];
          const float* Mrow = M + (size_t)i * O_DIM;
#pragma unroll
          for (int j = 0; j < 4; ++j) lat[j] += (double)Mrow[o[j]];
        }
      }
    }
    unsigned cur = 0;
#pragma unroll
    for (int j = 0; j < 4; ++j) {
      mem[j] = mem[j] * beta + (double)hv0[j] * ombeta + lat[j];
      double mthr = mem[j] * inv[j] - bth[j];
      bool s = mthr > 0.0;
      ob[(size_t)t * O_DIM + o[j]] = s ? 1.0f : 0.0f;
      unsigned long long mask = __ballot(s);
      if (s) {
        unsigned below = __builtin_amdgcn_mbcnt_lo((unsigned)mask, 0);
        below = __builtin_amdgcn_mbcnt_hi((unsigned)(mask >> 32), below);
        wlist[np][wv][cur + below] = (unsigned short)o[j];
      }
      cur += (unsigned)__popcll(mask);
      hv0[j] = hv1[j];
      hv1[j] = hv2[j];
    }
    if ((tid & 63) == 0) wcnt[np][wv] = (int)cur;
    __syncthreads();
    if (tid == 0)
      atomicAdd(&counts[t],
                wcnt[np][0] + wcnt[np][1] + wcnt[np][2] + wcnt[np][3]);
  }
}

__global__ void finalize_kernel(const int* __restrict__ counts,
                                float* __restrict__ out) {
  if (threadIdx.x == 0) {
    long long total = 0;
    int mx = 0;
    for (int t = 0; t < T_DIM; ++t) {
      total += counts[t];
      if (counts[t] > mx) mx = counts[t];
    }
    const double N = (double)B_DIM * T_DIM * O_DIM;
    out[(size_t)B_DIM * T_DIM * O_DIM] = (float)(0.5 * (double)total / N);
    out[(size_t)B_DIM * T_DIM * O_DIM + 1] =
        (float)((double)mx / (double)(B_DIM * O_DIM));
  }
}

extern "C" void kernel_launch(void* const* d_in, const int* in_sizes, int n_in,
                              void* d_out, int out_size, void* d_ws,
                              size_t ws_size, hipStream_t stream) {
  const float* x = (const float*)d_in[0];
  const float* w = (const float*)d_in[1];
  const float* v = (const float*)d_in[2];
  const float* beta = (const float*)d_in[3];
  const float* b = (const float*)d_in[4];
  float* out = (float*)d_out;

  char* ws = (char*)d_ws;
  const size_t OFF_M = 0;           // 4 MB
  const size_t OFF_H = 4194304;     // 50 MB
  const size_t OFF_WTH = 56623104;  // 2 MB
  const size_t OFF_WTL = 58720256;  // 2 MB
  const size_t OFF_NP = 60817408;   // 128 KB normpart[16][1024] f64
  const size_t OFF_CNT = 60948480;  // 512 B
  const size_t OFF_XTH = 60948992;  // 25 MB
  const size_t OFF_XTL = 87163392;  // 25 MB -> end 113377792
  float* M = (float*)(ws + OFF_M);
  float* h = (float*)(ws + OFF_H);
  unsigned short* wTth = (unsigned short*)(ws + OFF_WTH);
  unsigned short* wTtl = (unsigned short*)(ws + OFF_WTL);
  double* normpart = (double*)(ws + OFF_NP);
  int* counts = (int*)(ws + OFF_CNT);
  unsigned short* xth = (unsigned short*)(ws + OFF_XTH);
  unsigned short* xtl = (unsigned short*)(ws + OFF_XTL);
  const bool big_ws = ws_size >= (size_t)113377792;

  hipMemsetAsync(counts, 0, 512, stream);
  hipLaunchKernelGGL(split_wT_kernel, dim3(16, 16), dim3(256), 0, stream, w,
                     wTth, wTtl, normpart);
  if (big_ws)
    hipLaunchKernelGGL(xsplit_kernel, dim3(400), dim3(256), 0, stream, x, xth,
                       xtl);
  hipLaunchKernelGGL(mbuild_mfma, dim3(16, 16), dim3(256), 0, stream, wTth,
                     wTtl, v, beta, M);
  if (big_ws)
    hipLaunchKernelGGL(hgemm_direct, dim3(8, 100), dim3(256), 0, stream, xth,
                       xtl, wTth, wTtl, h);
  else
    hipLaunchKernelGGL(hgemm_lds, dim3(8, 100), dim3(256), 0, stream, x, wTth,
                       wTtl, h);
  hipLaunchKernelGGL(scan_kernel, dim3(128), dim3(256), 0, stream, h, M,
                     normpart, b, beta, out, counts);
  hipLaunchKernelGGL(finalize_kernel, dim3(1), dim3(64), 0, stream, counts,
                     out);
}

// Round 7
// 306.549 us; speedup vs baseline: 1.3705x; 1.3154x over previous
//
#include <hip/hip_runtime.h>
#include <cstdint>
#include <cstddef>

#define I_DIM 1024
#define O_DIM 1024
#define B_DIM 128
#define T_DIM 100
#define PANEL 32768  // fragment-tiled panel stride (ushorts) = 64q*64lane*8
#define QSTep 512    // per-q stride (ushorts) = 64 lanes * 8

typedef __attribute__((ext_vector_type(8))) __bf16 bf16x8;
typedef __attribute__((ext_vector_type(16))) float f32x16;

// Workgroup barrier that drains only LDS ops (lgkmcnt=0); global loads and
// stores stay in flight. simm16 = vm[3:0]=0xF | exp=7<<4 | lgkm=0<<8 |
// vm[5:4]=3<<14 = 0xC07F.
__device__ __forceinline__ void wg_barrier_lgkm() {
  __asm__ volatile("" ::: "memory");
  __builtin_amdgcn_s_waitcnt(0xC07F);
  __builtin_amdgcn_s_barrier();
  __asm__ volatile("" ::: "memory");
}

__device__ __forceinline__ unsigned short bf16rn(float x) {
  unsigned u = __float_as_uint(x);
  unsigned r = u + 0x7FFFu + ((u >> 16) & 1u);
  return (unsigned short)(r >> 16);
}
__device__ __forceinline__ void split2(float x, unsigned short& h,
                                       unsigned short& l) {
  h = bf16rn(x);
  float hf = __uint_as_float(((unsigned)h) << 16);
  l = bf16rn(x - hf);
}

// ---------------------------------------------------------------------------
// prep: fused split_wT (WGs 0..255) + xsplit (WGs 256..655).
// Layouts identical to R6 (validated).
// ---------------------------------------------------------------------------
__global__ __launch_bounds__(256) void prep_kernel(
    const float* __restrict__ w, const float* __restrict__ x,
    unsigned short* __restrict__ wTth, unsigned short* __restrict__ wTtl,
    unsigned short* __restrict__ xth, unsigned short* __restrict__ xtl,
    double* __restrict__ normpart) {
  __shared__ float tile[64][65];
  __shared__ double red[4][64];
  const int id = blockIdx.x;
  const int tid = threadIdx.x;
  if (id < 256) {  // ---- split_wT ----
    const int a0 = (id >> 4) * 64, o0 = (id & 15) * 64;
    const int tr = tid >> 4, tc4 = (tid & 15) * 4;
#pragma unroll
    for (int rr = 0; rr < 64; rr += 16) {
      float4 v = *(const float4*)&w[(size_t)(a0 + tr + rr) * O_DIM + o0 + tc4];
      tile[tr + rr][tc4 + 0] = v.x;
      tile[tr + rr][tc4 + 1] = v.y;
      tile[tr + rr][tc4 + 2] = v.z;
      tile[tr + rr][tc4 + 3] = v.w;
    }
    __syncthreads();
    {
      const int ol = tid & 63, seg = tid >> 6;
      double s = 0.0;
#pragma unroll
      for (int i = 0; i < 16; ++i) {
        double v = (double)tile[seg * 16 + i][ol];
        s += v * v;
      }
      red[seg][ol] = s;
    }
    const int q = (a0 >> 4) + (tc4 >> 4);
    const int kh = (tc4 >> 3) & 1;
    const int inner = tc4 & 7;
#pragma unroll
    for (int rr = 0; rr < 64; rr += 16) {
      int o = o0 + tr + rr;
      unsigned short hh[4], ll[4];
#pragma unroll
      for (int j = 0; j < 4; ++j) split2(tile[tc4 + j][tr + rr], hh[j], ll[j]);
      int l = (o & 31) + 32 * kh;
      size_t base = ((size_t)(o >> 5) * PANEL) + (size_t)q * QSTep +
                    (size_t)l * 8 + inner;
      *(ushort4*)&wTth[base] = make_ushort4(hh[0], hh[1], hh[2], hh[3]);
      *(ushort4*)&wTtl[base] = make_ushort4(ll[0], ll[1], ll[2], ll[3]);
    }
    __syncthreads();
    if (tid < 64)
      normpart[(size_t)(a0 >> 6) * O_DIM + o0 + tid] =
          red[0][tid] + red[1][tid] + red[2][tid] + red[3][tid];
  } else {  // ---- xsplit ----
    const int p = id - 256;
    const int wq = tid >> 6, lane = tid & 63;
    const int row = lane & 31, kh = lane >> 5;
    const float* src = x + (size_t)(p * 32 + row) * I_DIM + kh * 8;
#pragma unroll 4
    for (int i = 0; i < 16; ++i) {
      const int q = i * 4 + wq;
      const float* s = src + q * 16;
      float4 v0 = *(const float4*)(s);
      float4 v1 = *(const float4*)(s + 4);
      unsigned short h[8], l[8];
      split2(v0.x, h[0], l[0]);
      split2(v0.y, h[1], l[1]);
      split2(v0.z, h[2], l[2]);
      split2(v0.w, h[3], l[3]);
      split2(v1.x, h[4], l[4]);
      split2(v1.y, h[5], l[5]);
      split2(v1.z, h[6], l[6]);
      split2(v1.w, h[7], l[7]);
      size_t base = ((size_t)p * PANEL) + (size_t)q * QSTep + (size_t)lane * 8;
      *(ushort4*)&xth[base] = make_ushort4(h[0], h[1], h[2], h[3]);
      *(ushort4*)&xth[base + 4] = make_ushort4(h[4], h[5], h[6], h[7]);
      *(ushort4*)&xtl[base] = make_ushort4(l[0], l[1], l[2], l[3]);
      *(ushort4*)&xtl[base + 4] = make_ushort4(l[4], l[5], l[6], l[7]);
    }
  }
}

// ---------------------------------------------------------------------------
// gemm_fused: blockIdx.y < 100 -> hgemm (WG tile 128x64, wave 64x32, 1600
// WGs for 2x occupancy); blockIdx.y >= 100 -> mbuild (R6-validated, 64x64).
// Zero LDS, zero barriers. Per-acc MFMA order (q asc; hh,hl,lh) identical
// to R6 -> bit-identical h and M.
// ---------------------------------------------------------------------------
__global__ __launch_bounds__(256) void gemm_fused(
    const unsigned short* __restrict__ xth,
    const unsigned short* __restrict__ xtl,
    const unsigned short* __restrict__ wTth,
    const unsigned short* __restrict__ wTtl, const float* __restrict__ v,
    const float* __restrict__ beta_p, float* __restrict__ h,
    float* __restrict__ M) {
  const int tid = threadIdx.x;
  const int wv = tid >> 6, lane = tid & 63;
  const int lm = lane & 31, lkh = lane >> 5;
  if (blockIdx.y < 100) {  // ---------------- hgemm ----------------
    const int row0 = blockIdx.y * 128, col0 = blockIdx.x * 64;
    const int wm = wv >> 1, wn = wv & 1;
    f32x16 acc[2];
#pragma unroll
    for (int a = 0; a < 2; ++a)
#pragma unroll
      for (int e = 0; e < 16; ++e) acc[a][e] = 0.f;
    const unsigned short *pah[2], *pal[2], *pbh, *pbl;
#pragma unroll
    for (int mt = 0; mt < 2; ++mt) {
      size_t offA =
          ((size_t)((row0 >> 5) + wm * 2 + mt) * PANEL) + (size_t)lane * 8;
      pah[mt] = xth + offA;
      pal[mt] = xtl + offA;
    }
    {
      size_t offB = ((size_t)((col0 >> 5) + wn) * PANEL) + (size_t)lane * 8;
      pbh = wTth + offB;
      pbl = wTtl + offB;
    }
    bf16x8 fah[2][2], fal[2][2], fbh[2], fbl[2];  // [buf][tile] / [buf]
#pragma unroll
    for (int mt = 0; mt < 2; ++mt) {
      fah[0][mt] = *(const bf16x8*)(pah[mt]);
      fal[0][mt] = *(const bf16x8*)(pal[mt]);
    }
    fbh[0] = *(const bf16x8*)(pbh);
    fbl[0] = *(const bf16x8*)(pbl);
#pragma unroll 2
    for (int q = 0; q < 64; ++q) {
      const int cb = q & 1;
      if (q < 63) {
        size_t d = (size_t)(q + 1) * QSTep;
#pragma unroll
        for (int mt = 0; mt < 2; ++mt) {
          fah[cb ^ 1][mt] = *(const bf16x8*)(pah[mt] + d);
          fal[cb ^ 1][mt] = *(const bf16x8*)(pal[mt] + d);
        }
        fbh[cb ^ 1] = *(const bf16x8*)(pbh + d);
        fbl[cb ^ 1] = *(const bf16x8*)(pbl + d);
      }
#pragma unroll
      for (int mt = 0; mt < 2; ++mt)
        acc[mt] = __builtin_amdgcn_mfma_f32_32x32x16_bf16(fah[cb][mt], fbh[cb],
                                                          acc[mt], 0, 0, 0);
#pragma unroll
      for (int mt = 0; mt < 2; ++mt)
        acc[mt] = __builtin_amdgcn_mfma_f32_32x32x16_bf16(fah[cb][mt], fbl[cb],
                                                          acc[mt], 0, 0, 0);
#pragma unroll
      for (int mt = 0; mt < 2; ++mt)
        acc[mt] = __builtin_amdgcn_mfma_f32_32x32x16_bf16(fal[cb][mt], fbh[cb],
                                                          acc[mt], 0, 0, 0);
    }
    const int col = col0 + wn * 32 + lm;
#pragma unroll
    for (int mt = 0; mt < 2; ++mt)
#pragma unroll
      for (int r = 0; r < 16; ++r) {
        int row = row0 + wm * 64 + mt * 32 + (r & 3) + 8 * (r >> 2) + 4 * lkh;
        h[(size_t)row * O_DIM + col] = acc[mt][r];
      }
  } else {  // ---------------- mbuild ----------------
    const int i0 = (blockIdx.y - 100) * 64, o0 = blockIdx.x * 64;
    const int wm = wv >> 1, wn = wv & 1;
    f32x16 acc;
#pragma unroll
    for (int e = 0; e < 16; ++e) acc[e] = 0.f;
    const size_t offA = ((size_t)((i0 >> 5) + wm) * PANEL) + (size_t)lane * 8;
    const size_t offB = ((size_t)((o0 >> 5) + wn) * PANEL) + (size_t)lane * 8;
    bf16x8 ah[2], al[2], bh[2], bl[2];
    ah[0] = *(const bf16x8*)(wTth + offA);
    al[0] = *(const bf16x8*)(wTtl + offA);
    bh[0] = *(const bf16x8*)(wTth + offB);
    bl[0] = *(const bf16x8*)(wTtl + offB);
#pragma unroll 2
    for (int q = 0; q < 64; ++q) {
      const int cb = q & 1;
      if (q < 63) {
        size_t d = (size_t)(q + 1) * QSTep;
        ah[cb ^ 1] = *(const bf16x8*)(wTth + offA + d);
        al[cb ^ 1] = *(const bf16x8*)(wTtl + offA + d);
        bh[cb ^ 1] = *(const bf16x8*)(wTth + offB + d);
        bl[cb ^ 1] = *(const bf16x8*)(wTtl + offB + d);
      }
      acc =
          __builtin_amdgcn_mfma_f32_32x32x16_bf16(ah[cb], bh[cb], acc, 0, 0, 0);
      acc =
          __builtin_amdgcn_mfma_f32_32x32x16_bf16(ah[cb], bl[cb], acc, 0, 0, 0);
      acc =
          __builtin_amdgcn_mfma_f32_32x32x16_bf16(al[cb], bh[cb], acc, 0, 0, 0);
    }
    const float beta = beta_p[0];
    const float ombeta = 1.0f - beta;
    const int col = o0 + wn * 32 + lm;
#pragma unroll
    for (int r = 0; r < 16; ++r) {
      int row = i0 + wm * 32 + (r & 3) + 8 * (r >> 2) + 4 * lkh;
      M[(size_t)row * O_DIM + col] =
          ombeta * v[(size_t)row * O_DIM + col] - beta * acc[r];
    }
  }
}

// ---------------------------------------------------------------------------
// Scan: lgkm-only barrier per step (global stores / h prefetches stay in
// flight); per-WG spike counts via plain stores to wgcnt[b][t] (no atomics).
// ---------------------------------------------------------------------------
__global__ __launch_bounds__(256) void scan_kernel(
    const float* __restrict__ h, const float* __restrict__ M,
    const double* __restrict__ normpart, const float* __restrict__ bvec,
    const float* __restrict__ beta_p, float* __restrict__ out,
    int* __restrict__ wgcnt) {
  __shared__ unsigned short wlist[2][4][256];
  __shared__ int wcnt[2][4];
  const int b = blockIdx.x, tid = threadIdx.x;
  const int wv = tid >> 6;
  const double beta = (double)beta_p[0];
  const double ombeta = 1.0 - beta;
  double mem[4] = {0.0, 0.0, 0.0, 0.0};
  double inv[4], bth[4];
  int o[4];
#pragma unroll
  for (int j = 0; j < 4; ++j) {
    o[j] = tid + j * 256;
    double s = 0.0;
#pragma unroll
    for (int g = 0; g < 16; ++g) s += normpart[(size_t)g * O_DIM + o[j]];
    inv[j] = 1.0 / (s + 1e-8);
    bth[j] = (double)bvec[o[j]];
  }
  if (tid < 8) wcnt[tid >> 2][tid & 3] = 0;
  __syncthreads();
  const float* hb = h + (size_t)b * T_DIM * O_DIM;
  float* ob = out + (size_t)b * T_DIM * O_DIM;
  float hv0[4], hv1[4];
#pragma unroll
  for (int j = 0; j < 4; ++j) {
    hv0[j] = hb[o[j]];
    hv1[j] = hb[O_DIM + o[j]];
  }
  for (int t = 0; t < T_DIM; ++t) {
    const int p = t & 1, np = p ^ 1;
    float hv2[4] = {0.f, 0.f, 0.f, 0.f};
    if (t + 2 < T_DIM) {
#pragma unroll
      for (int j = 0; j < 4; ++j) hv2[j] = hb[(size_t)(t + 2) * O_DIM + o[j]];
    }
    double lat[4] = {0.0, 0.0, 0.0, 0.0};
    const int ks = wcnt[p][0] + wcnt[p][1] + wcnt[p][2] + wcnt[p][3];
    if (ks) {
#pragma unroll
      for (int w = 0; w < 4; ++w) {
        const int kw = wcnt[p][w];
        for (int n = 0; n < kw; ++n) {
          const int i = wlist[p][w][n];
          const float* Mrow = M + (size_t)i * O_DIM;
#pragma unroll
          for (int j = 0; j < 4; ++j) lat[j] += (double)Mrow[o[j]];
        }
      }
    }
    unsigned cur = 0;
#pragma unroll
    for (int j = 0; j < 4; ++j) {
      mem[j] = mem[j] * beta + (double)hv0[j] * ombeta + lat[j];
      double mthr = mem[j] * inv[j] - bth[j];
      bool s = mthr > 0.0;
      ob[(size_t)t * O_DIM + o[j]] = s ? 1.0f : 0.0f;
      unsigned long long mask = __ballot(s);
      if (s) {
        unsigned below = __builtin_amdgcn_mbcnt_lo((unsigned)mask, 0);
        below = __builtin_amdgcn_mbcnt_hi((unsigned)(mask >> 32), below);
        wlist[np][wv][cur + below] = (unsigned short)o[j];
      }
      cur += (unsigned)__popcll(mask);
      hv0[j] = hv1[j];
      hv1[j] = hv2[j];
    }
    if ((tid & 63) == 0) wcnt[np][wv] = (int)cur;
    wg_barrier_lgkm();
    if (tid == 0)
      wgcnt[b * T_DIM + t] =
          wcnt[np][0] + wcnt[np][1] + wcnt[np][2] + wcnt[np][3];
  }
}

// ---------------------------------------------------------------------------
// finalize: counts[t] = sum_b wgcnt[b][t]; loss & spread from exact ints.
// ---------------------------------------------------------------------------
__global__ void finalize_kernel(const int* __restrict__ wgcnt,
                                float* __restrict__ out) {
  __shared__ int sums[128];
  const int t = threadIdx.x;  // 128 threads
  int s = 0;
  if (t < T_DIM) {
    for (int b = 0; b < B_DIM; ++b) s += wgcnt[b * T_DIM + t];
  }
  sums[t] = s;
  __syncthreads();
  if (t == 0) {
    long long total = 0;
    int mx = 0;
    for (int i = 0; i < T_DIM; ++i) {
      total += sums[i];
      if (sums[i] > mx) mx = sums[i];
    }
    const double N = (double)B_DIM * T_DIM * O_DIM;
    out[(size_t)B_DIM * T_DIM * O_DIM] = (float)(0.5 * (double)total / N);
    out[(size_t)B_DIM * T_DIM * O_DIM + 1] =
        (float)((double)mx / (double)(B_DIM * O_DIM));
  }
}

extern "C" void kernel_launch(void* const* d_in, const int* in_sizes, int n_in,
                              void* d_out, int out_size, void* d_ws,
                              size_t ws_size, hipStream_t stream) {
  const float* x = (const float*)d_in[0];
  const float* w = (const float*)d_in[1];
  const float* v = (const float*)d_in[2];
  const float* beta = (const float*)d_in[3];
  const float* b = (const float*)d_in[4];
  float* out = (float*)d_out;

  char* ws = (char*)d_ws;
  const size_t OFF_M = 0;           // 4 MB
  const size_t OFF_H = 4194304;     // 50 MB
  const size_t OFF_WTH = 56623104;  // 2 MB
  const size_t OFF_WTL = 58720256;  // 2 MB
  const size_t OFF_NP = 60817408;   // 128 KB
  const size_t OFF_XTH = 60948992;  // 25 MB
  const size_t OFF_XTL = 87163392;  // 25 MB -> end 113377792 (proven fits)
  float* M = (float*)(ws + OFF_M);
  float* h = (float*)(ws + OFF_H);
  unsigned short* wTth = (unsigned short*)(ws + OFF_WTH);
  unsigned short* wTtl = (unsigned short*)(ws + OFF_WTL);
  double* normpart = (double*)(ws + OFF_NP);
  unsigned short* xth = (unsigned short*)(ws + OFF_XTH);
  unsigned short* xtl = (unsigned short*)(ws + OFF_XTL);
  // wgcnt reuses the (dead-by-then) xth region: gemm finished before scan.
  int* wgcnt = (int*)(ws + OFF_XTH);

  hipLaunchKernelGGL(prep_kernel, dim3(656), dim3(256), 0, stream, w, x, wTth,
                     wTtl, xth, xtl, normpart);
  hipLaunchKernelGGL(gemm_fused, dim3(16, 116), dim3(256), 0, stream, xth, xtl,
                     wTth, wTtl, v, beta, h, M);
  hipLaunchKernelGGL(scan_kernel, dim3(128), dim3(256), 0, stream, h, M,
                     normpart, b, beta, out, wgcnt);
  hipLaunchKernelGGL(finalize_kernel, dim3(1), dim3(128), 0, stream, wgcnt,
                     out);
}